// Round 1
// 111.743 us; speedup vs baseline: 1.0003x; 1.0003x over previous
//
#include <hip/hip_runtime.h>
#include <hip/hip_bf16.h>
#include <stdint.h>

typedef unsigned int u32;

#define BATCH 64
#define ROOT 128
#define NLEAF 7
#define LHEAD 4
#define HDIM 128
#define NNODES 1024
#define OUTROWS 1025
#define NREL1 65          // NUM_REL + 1
#define PSTR 132          // padded LDS row stride (dwords)

typedef __attribute__((ext_vector_type(8))) short bf16x8;
typedef __attribute__((ext_vector_type(4))) float f32x4;

// Per-relation precomputed (rewritten every launch — idempotent):
//   g_Mfrag = M as bf16 in MFMA A-fragment order:
//     uint4 index per rel: (rt*4 + kt)*64 + lane
//     holds M[i=rt*16+(lane&15)][k=kt*32+(lane>>4)*8 + 0..7]
//   g_Re / g_Ro = deinterleaved rel_emb: g_Re[rel][i] = r[2i], g_Ro[rel][i] = r[2i+1]
__device__ u32   g_Mfrag[NREL1 * 8192];
__device__ float g_Re[NREL1 * HDIM];
__device__ float g_Ro[NREL1 * HDIM];

static __device__ __forceinline__ u32 rne_bf16(float f) {
    u32 u = __builtin_bit_cast(u32, f);
    return (u + 0x7fffu + ((u >> 16) & 1u)) >> 16;
}
static __device__ __forceinline__ u32 pack_bf16(float a, float b) {
    return rne_bf16(a) | (rne_bf16(b) << 16);
}

// ---------------------------------------------------------------------------
// prep_kernel: grid (65, 5), block 256.
//  part 0..3 : pack one quarter of M[rel] into g_Mfrag (A-fragment order)
//  part 4    : deinterleave rel_emb[rel] into g_Re / g_Ro
// ---------------------------------------------------------------------------
__global__ void prep_kernel(const float* __restrict__ rel_mat,
                            const float* __restrict__ rel_emb) {
    int rel = blockIdx.x;
    int part = blockIdx.y;
    const float* M = rel_mat + (size_t)rel * HDIM * HDIM;

    if (part < 4) {
        u32* dst = &g_Mfrag[(size_t)rel * 8192];
        #pragma unroll
        for (int q = 0; q < 8; ++q) {
            int o = part * 2048 + q * 256 + threadIdx.x;   // 0..8191 dwords
            int r  = o >> 10;
            int t  = (o >> 8) & 3;
            int ln = (o >> 2) & 63;
            int dw = o & 3;
            int i = r * 16 + (ln & 15);
            int j = t * 32 + ((ln >> 4) << 3) + dw * 2;
            dst[o] = pack_bf16(M[i * HDIM + j], M[i * HDIM + j + 1]);
        }
    } else {
        int i = threadIdx.x;                               // 0..255
        float v = rel_emb[(size_t)rel * 2 * HDIM + i];
        if (i & 1) g_Ro[rel * HDIM + (i >> 1)] = v;
        else       g_Re[rel * HDIM + (i >> 1)] = v;
    }
}

// ---------------------------------------------------------------------------
// triple_kernel: grid (32, 64), 4 waves/block, ONE WAVE = ONE TRIPLE, zero
// __syncthreads.
//
// MFMA B operand packs ALL 11 embed rows: cols 0..3 = he[0..3], cols 4..10 =
// te[0..6] (cols 11..15 junk, never read). One MFMA pass yields both
// Mh = M·he (for the epilogue, via MhT LDS transpose) and Mt = M·te (consumed
// in-register for the score dots):
//   b[l] = r_odd  · Mh[:,l]   (lane col nn<4  uses g_Ro)
//   a[t] = r_even · Mt[:,t]   (lane col nn>=4 uses g_Re)
// Each lane dots its own column against its 4 accumulator rows per rt-tile
// (32 FMAs), then a 2-step xor butterfly (lanes 16 apart share a column) +
// 11 const-lane shfl broadcasts replace the old 11×6 swizzle reductions.
//
// B fragments load DIRECTLY from atom in fragment order (gathered but each
// byte of the 11 rows read exactly once, L2/L3-hot) — no he_s staging.
// LDS only for the MhT transpose (padded stride 132).
// ---------------------------------------------------------------------------
__global__ __launch_bounds__(256) void triple_kernel(
    const int* __restrict__ tok,
    const int* __restrict__ leaf_rel,
    const float* __restrict__ atom,
    const float* __restrict__ gtok,
    float* __restrict__ out)
{
    int g = blockIdx.x;                 // 4 roots per block
    int b = blockIdx.y;
    int tid = threadIdx.x;
    int wave = tid >> 6, lane = tid & 63;
    int rn = g * 4 + wave;

    __shared__ __align__(16) float MhT[4][LHEAD][PSTR];    // [wave][l][i]

    int rel = leaf_rel[b * ROOT + rn];  // wave-uniform

    // ---- tokens: lanes 0..10 load; lane l holds the token for B-col l ----
    int tokidx = 0;
    if (lane < LHEAD + NLEAF) {
        int pos;
        if (lane < LHEAD) { int hp = rn + lane; if (hp > ROOT - 1) hp = ROOT - 1; pos = hp; }
        else              pos = ROOT + rn * NLEAF + (lane - LHEAD);
        tokidx = tok[b * NNODES + pos];
    }

    int nn = lane & 15;                  // MFMA col
    int kb = (lane >> 4) << 3;           // k-chunk base within 32-wide k-tile
    int sel = (nn < LHEAD + NLEAF) ? nn : 0;
    int tokrow = __shfl(tokidx, sel, 64);          // token of this lane's B-col

    // ---- epilogue rows (lane-linear, fp32) ----
    float te_lo[NLEAF], te_hi[NLEAF];
    #pragma unroll
    for (int t = 0; t < NLEAF; ++t) {
        int tt = __shfl(tokidx, LHEAD + t, 64);
        const float* r = atom + (size_t)tt * HDIM;
        te_lo[t] = r[lane]; te_hi[t] = r[lane + 64];
    }
    int h0 = __shfl(tokidx, 0, 64);
    const float* hr = atom + (size_t)h0 * HDIM;
    float he0_lo = hr[lane], he0_hi = hr[lane + 64];

    // ---- B fragments: direct gather from atom in fragment order ----
    const float* arow = atom + (size_t)tokrow * HDIM + kb;
    uint4 bfr[4];
    #pragma unroll
    for (int kt = 0; kt < 4; ++kt) {
        float4 f0 = *(const float4*)(arow + kt * 32);
        float4 f1 = *(const float4*)(arow + kt * 32 + 4);
        bfr[kt].x = pack_bf16(f0.x, f0.y);
        bfr[kt].y = pack_bf16(f0.z, f0.w);
        bfr[kt].z = pack_bf16(f1.x, f1.y);
        bfr[kt].w = pack_bf16(f1.z, f1.w);
    }

    // ---- per-rt rel_emb fragments (rows row0..row0+3 of even or odd half) ----
    const float* rbase = ((nn < LHEAD) ? g_Ro : g_Re) + rel * HDIM + ((lane >> 4) << 2);
    float4 rreg[8];
    #pragma unroll
    for (int rt = 0; rt < 8; ++rt) rreg[rt] = *(const float4*)(rbase + rt * 16);

    // ---- MFMA: 8 row-tiles; harvest Mh into LDS, dot Mt/Mh into dp ----
    const uint4* Mf = ((const uint4*)g_Mfrag) + (size_t)rel * 2048;
    float dp = 0.f;
    #pragma unroll
    for (int rt = 0; rt < 8; ++rt) {
        f32x4 acc = {0.f, 0.f, 0.f, 0.f};
        #pragma unroll
        for (int kt = 0; kt < 4; ++kt) {
            uint4 afr = Mf[(rt * 4 + kt) * 64 + lane];
            acc = __builtin_amdgcn_mfma_f32_16x16x32_bf16(
                      __builtin_bit_cast(bf16x8, afr),
                      __builtin_bit_cast(bf16x8, bfr[kt]), acc, 0, 0, 0);
        }
        dp += rreg[rt].x * acc[0] + rreg[rt].y * acc[1]
            + rreg[rt].z * acc[2] + rreg[rt].w * acc[3];
        if (nn < LHEAD) {                       // D: col=lane&15, row=(lane>>4)*4+reg
            int row0 = rt * 16 + ((lane >> 4) << 2);
            *(float4*)&MhT[wave][nn][row0] = make_float4(acc[0], acc[1], acc[2], acc[3]);
        }
    }

    // ---- finish dots: 4 lanes (16 apart) share each column ----
    dp += __shfl_xor(dp, 16, 64);
    dp += __shfl_xor(dp, 32, 64);

    float b_r[LHEAD], a_r[NLEAF];
    #pragma unroll
    for (int l = 0; l < LHEAD; ++l) b_r[l] = __shfl(dp, l, 64);
    #pragma unroll
    for (int t = 0; t < NLEAF; ++t) a_r[t] = __shfl(dp, LHEAD + t, 64);

    // ---- root row (= he[0]) + graph token ----
    size_t bbase = (size_t)b * OUTROWS * HDIM;
    out[bbase + (size_t)(1 + rn) * HDIM + lane]      = he0_lo;
    out[bbase + (size_t)(1 + rn) * HDIM + lane + 64] = he0_hi;
    if (g == 0 && wave == 0) {
        out[bbase + lane]      = gtok[lane];
        out[bbase + lane + 64] = gtok[lane + 64];
    }

    // ---- epilogue: per tail, alpha in regs (uniform), te from regs ----
    size_t obase = bbase + (size_t)(1 + ROOT + rn * NLEAF) * HDIM;
    #pragma unroll
    for (int t = 0; t < NLEAF; ++t) {
        float sc[LHEAD]; float mx = -1e30f;
        #pragma unroll
        for (int l = 0; l < LHEAD; ++l) {
            float x = a_r[t] + b_r[l];
            x = (x >= 0.f) ? x : 0.01f * x;          // leaky_relu 0.01
            sc[l] = x; mx = fmaxf(mx, x);
        }
        float sum = 0.f;
        #pragma unroll
        for (int l = 0; l < LHEAD; ++l) { sc[l] = __expf(sc[l] - mx); sum += sc[l]; }
        float inv = 1.f / sum;
        float r0 = te_lo[t], r1 = te_hi[t];
        #pragma unroll
        for (int l = 0; l < LHEAD; ++l) {
            float al = sc[l] * inv;
            r0 += al * MhT[wave][l][lane];
            r1 += al * MhT[wave][l][lane + 64];
        }
        out[obase + t * HDIM + lane]      = r0;
        out[obase + t * HDIM + lane + 64] = r1;
    }
}

// ---------------------------------------------------------------------------
extern "C" void kernel_launch(void* const* d_in, const int* in_sizes, int n_in,
                              void* d_out, int out_size, void* d_ws, size_t ws_size,
                              hipStream_t stream) {
    (void)in_sizes; (void)n_in; (void)out_size; (void)d_ws; (void)ws_size;
    const int* tok       = (const int*)d_in[0];     // [B,1024,1] int32
    const int* leaf_rel  = (const int*)d_in[1];     // [B,128]    int32
    // d_in[2] = head_lengths: unused by the reference body
    const float* atom    = (const float*)d_in[3];   // [30000,128] fp32
    const float* rel_mat = (const float*)d_in[4];   // [65,128*128] fp32
    const float* rel_emb = (const float*)d_in[5];   // [65,256] fp32
    const float* gtok    = (const float*)d_in[6];   // [1,128] fp32
    float* out = (float*)d_out;                     // [64,1025,128] fp32

    dim3 pgrid(NREL1, 5);
    prep_kernel<<<pgrid, 256, 0, stream>>>(rel_mat, rel_emb);

    dim3 grid(ROOT / 4, BATCH);
    triple_kernel<<<grid, 256, 0, stream>>>(tok, leaf_rel, atom, gtok, out);
}